// Round 3
// baseline (140.622 us; speedup 1.0000x reference)
//
#include <hip/hip_runtime.h>
#include <cstddef>

// Problem constants
#define BB   8
#define CC   64
#define H1   128
#define W1   128
#define HW1  (H1*W1)
#define HS   60
#define WS   60
#define HO   129
#define WO   129

// padded normalized-x1 plane
#define PWD  144            // padded width (floats), 16B aligned
#define PHT  134            // padded height
#define PPL  (PHT*PWD)      // 19296 floats per (b,c) plane

// conv tiling
#define G     16            // channel groups
#define CPG   4             // channels per group
#define T4    19            // float4 per LDS tile row (76 floats: 4-way bank alias max)
#define TROWS 70            // tile rows (64 outputs + 5 taps + 1 edge row)
#define NSLOT (TROWS*T4)    // 1330 float4 slots per buffer
#define PSTR  132           // partial plane row stride
#define PPLANE (HO*PSTR)    // 17028

typedef unsigned int u32;
__device__ __forceinline__ void async_g2l(const float* g, float4* l) {
    __builtin_amdgcn_global_load_lds((const __attribute__((address_space(1))) u32*)g,
                                     (__attribute__((address_space(3))) u32*)l,
                                     16, 0, 0);
}

// ---------------------------------------------------------------------------
// normalize x1 channel-wise and write into zero-padded planes
__global__ __launch_bounds__(256) void k_norm1(const float* __restrict__ x1,
                                               float* __restrict__ x1n) {
    int idx = blockIdx.x * 256 + threadIdx.x;    // 8*19296 = 154368 exactly
    int b  = idx / PPL;
    int pp = idx - b * PPL;
    int pr = pp / PWD, pc = pp - pr * PWD;
    int gy = pr - 3, gx = pc - 3;
    float* outp = x1n + (size_t)b * CC * PPL + pp;
    if ((unsigned)gy < 128u && (unsigned)gx < 128u) {
        const float* p = x1 + (size_t)b * CC * HW1 + gy * W1 + gx;
        float v[CC];
        float s = 0.f;
#pragma unroll
        for (int c = 0; c < CC; ++c) { v[c] = p[c * HW1]; s += v[c] * v[c]; }
        float inv = 1.0f / sqrtf(s);
#pragma unroll
        for (int c = 0; c < CC; ++c) outp[c * PPL] = v[c] * inv;
    } else {
#pragma unroll
        for (int c = 0; c < CC; ++c) outp[c * PPL] = 0.f;
    }
}

// 4-way channel-split inv-norm of x2
__global__ __launch_bounds__(256) void k_inv2(const float* __restrict__ x2,
                                              float* __restrict__ inv2) {
    __shared__ float red[256];
    int tid = threadIdx.x;
    int pix = blockIdx.x * 64 + (tid & 63);
    int csub = tid >> 6;
    int b  = pix / (HS * WS);
    int hw = pix % (HS * WS);
    const float* p = x2 + ((size_t)b * CC + csub * 16) * (HS * WS) + hw;
    float s = 0.f;
#pragma unroll
    for (int c = 0; c < 16; ++c) {
        float v = p[c * (HS * WS)];
        s += v * v;
    }
    red[tid] = s;
    __syncthreads();
    if (tid < 64) {
        float t = red[tid] + red[tid + 64] + red[tid + 128] + red[tid + 192];
        inv2[blockIdx.x * 64 + tid] = 1.0f / sqrtf(t);
    }
}

// fold 10x10 patch grid into 6x6 kernel per (b,c)
__global__ __launch_bounds__(256) void k_fold(const float* __restrict__ x2,
                                              const float* __restrict__ inv2,
                                              float* __restrict__ S) {
    __shared__ float bins[36];
    int tid = threadIdx.x;
    int bc  = blockIdx.x;
    int b   = bc >> 6;
    if (tid < 36) bins[tid] = 0.f;
    __syncthreads();
    const float* px = x2 + (size_t)bc * (HS * WS);
    const float* pn = inv2 + b * (HS * WS);
    for (int i = tid; i < HS * WS; i += 256) {
        int hh = i / WS, ww = i - hh * WS;
        int bin = (hh % 6) * 6 + (ww % 6);
        atomicAdd(&bins[bin], px[i] * pn[i]);
    }
    __syncthreads();
    if (tid < 36) S[bc * 36 + tid] = bins[tid];
}

// ---------------------------------------------------------------------------
// conv: 64x64 output tile (+ guarded edge row/col 128), 4 channels/block,
// async global->LDS double-buffered, 4x4(+edges) outputs per thread
__global__ __launch_bounds__(256) void k_conv(const float* __restrict__ x1n,
                                              const float* __restrict__ S,
                                              float* __restrict__ part) {
    int blk = blockIdx.x;            // 4*8*16 = 512
    int x0 = (blk & 1) * 64;
    int y0 = ((blk >> 1) & 1) * 64;
    int b  = (blk >> 2) & 7;
    int g  = blk >> 5;
    int tid = threadIdx.x;
    int tx = tid & 15, ty = tid >> 4;
    int wv = tid >> 6;

    __shared__ float4 lbuf[2][NSLOT];
    __shared__ float4 svf[CPG][9];

    if (tid < CPG * 36)
        ((float*)svf)[tid] = S[((size_t)b * CC + g * CPG) * 36 + tid];

    // slot -> padded-plane offsets (channel-invariant)
    int off[6];
#pragma unroll
    for (int k = 0; k < 6; ++k) {
        int i = tid + 256 * k;
        int r = i / T4, c4 = i - r * T4;
        off[k] = (y0 + r) * PWD + x0 + 4 * c4;
    }

    const float* gbase = x1n + ((size_t)b * CC + g * CPG) * PPL;

    // prefetch channel 0 into buffer 0
#pragma unroll
    for (int k = 0; k < 5; ++k)
        async_g2l(gbase + off[k], &lbuf[0][wv * 64 + 256 * k]);
    if (tid < NSLOT - 1280)
        async_g2l(gbase + off[5], &lbuf[0][wv * 64 + 1280]);

    float acc[4][5] = {{0,0,0,0,0},{0,0,0,0,0},{0,0,0,0,0},{0,0,0,0,0}};
    float accE[5] = {0,0,0,0,0};
    const bool doC4 = (x0 == 64) && (tx == 15);
    const bool doR4 = (y0 == 64) && (ty == 15);

    for (int ci = 0; ci < CPG; ++ci) {
        __syncthreads();             // drains async loads for channel ci (+sv writes)

        if (ci + 1 < CPG) {          // prefetch next channel into other buffer
            const float* gp = gbase + (size_t)(ci + 1) * PPL;
            float4* dst = lbuf[(ci + 1) & 1];
#pragma unroll
            for (int k = 0; k < 5; ++k)
                async_g2l(gp + off[k], &dst[wv * 64 + 256 * k]);
            if (tid < NSLOT - 1280)
                async_g2l(gp + off[5], &dst[wv * 64 + 1280]);
        }

        float s[36];
        const float4* sp = (const float4*)svf[ci];
#pragma unroll
        for (int t = 0; t < 9; ++t) {
            float4 w = sp[t];
            s[4*t] = w.x; s[4*t+1] = w.y; s[4*t+2] = w.z; s[4*t+3] = w.w;
        }

        const float4* tb = lbuf[ci & 1];
#pragma unroll
        for (int rr = 0; rr < 9; ++rr) {
            const float4* rp = tb + (4 * ty + rr) * T4 + tx;
            float4 q0 = rp[0], q1 = rp[1], q2 = rp[2];
            float r[12] = {q0.x,q0.y,q0.z,q0.w, q1.x,q1.y,q1.z,q1.w,
                           q2.x,q2.y,q2.z,q2.w};
#pragma unroll
            for (int q = 0; q < 4; ++q) {
                int dy = rr - q;
                if (dy >= 0 && dy < 6) {
#pragma unroll
                    for (int j = 0; j < 4; ++j)
#pragma unroll
                        for (int dx = 0; dx < 6; ++dx)
                            acc[q][j] += r[j + dx] * s[dy * 6 + dx];
                    if (doC4) {
#pragma unroll
                        for (int dx = 0; dx < 6; ++dx)
                            acc[q][4] += r[4 + dx] * s[dy * 6 + dx];
                    }
                }
            }
            if (doR4 && rr >= 4) {
                int dy = rr - 4;
#pragma unroll
                for (int j = 0; j < 4; ++j)
#pragma unroll
                    for (int dx = 0; dx < 6; ++dx)
                        accE[j] += r[j + dx] * s[dy * 6 + dx];
                if (doC4) {
#pragma unroll
                    for (int dx = 0; dx < 6; ++dx)
                        accE[4] += r[4 + dx] * s[dy * 6 + dx];
                }
            }
        }
        if (doR4) {                  // window row rr=9 feeds edge row, dy=5
            const float4* rp = tb + (4 * ty + 9) * T4 + tx;
            float4 q0 = rp[0], q1 = rp[1], q2 = rp[2];
            float r[12] = {q0.x,q0.y,q0.z,q0.w, q1.x,q1.y,q1.z,q1.w,
                           q2.x,q2.y,q2.z,q2.w};
#pragma unroll
            for (int j = 0; j < 4; ++j)
#pragma unroll
                for (int dx = 0; dx < 6; ++dx)
                    accE[j] += r[j + dx] * s[30 + dx];
            if (doC4) {
#pragma unroll
                for (int dx = 0; dx < 6; ++dx)
                    accE[4] += r[4 + dx] * s[30 + dx];
            }
        }
    }

    float* pb = part + ((size_t)g * BB + b) * PPLANE;
    int orow = y0 + 4 * ty, ocol = x0 + 4 * tx;
#pragma unroll
    for (int q = 0; q < 4; ++q)
        *(float4*)(pb + (size_t)(orow + q) * PSTR + ocol) =
            make_float4(acc[q][0], acc[q][1], acc[q][2], acc[q][3]);
    if (doC4) {
#pragma unroll
        for (int q = 0; q < 4; ++q)
            pb[(size_t)(orow + q) * PSTR + 128] = acc[q][4];
    }
    if (doR4) {
        *(float4*)(pb + (size_t)128 * PSTR + ocol) =
            make_float4(accE[0], accE[1], accE[2], accE[3]);
        if (doC4) pb[(size_t)128 * PSTR + 128] = accE[4];
    }
}

// reduce 16 partials -> out129 (applies 1/3600)
__global__ __launch_bounds__(256) void k_reduce(const float* __restrict__ part,
                                                float* __restrict__ out129) {
    int idx = blockIdx.x * 256 + threadIdx.x;
    if (idx >= BB * HO * WO) return;
    int b = idx / (HO * WO);
    int p = idx % (HO * WO);
    int row = p / WO, col = p - row * WO;
    float s = 0.f;
#pragma unroll
    for (int g = 0; g < G; ++g)
        s += part[((size_t)g * BB + b) * PPLANE + (size_t)row * PSTR + col];
    out129[idx] = s * (1.0f / 3600.0f);
}

// jax.image.resize bilinear antialias=True, 129 -> 128, half-pixel
__global__ __launch_bounds__(256) void k_resize(const float* __restrict__ out129,
                                                float* __restrict__ out) {
    int idx = blockIdx.x * 256 + threadIdx.x;
    int b  = idx >> 14;
    int oy = (idx >> 7) & 127;
    int ox = idx & 127;

    const float inv_scale = 129.0f / 128.0f;
    const float ksc       = 128.0f / 129.0f;

    float sy = (oy + 0.5f) * inv_scale - 0.5f;
    float sx = (ox + 0.5f) * inv_scale - 0.5f;
    int fy = (int)floorf(sy);
    int fx = (int)floorf(sx);

    float wy[4], wx[4];
    float sumy = 0.f, sumx = 0.f;
#pragma unroll
    for (int k = 0; k < 4; ++k) {
        int jy = fy - 1 + k;
        float w = 0.f;
        if (jy >= 0 && jy < HO) w = fmaxf(0.f, 1.0f - fabsf(sy - (float)jy) * ksc);
        wy[k] = w; sumy += w;
        int jx = fx - 1 + k;
        float w2 = 0.f;
        if (jx >= 0 && jx < WO) w2 = fmaxf(0.f, 1.0f - fabsf(sx - (float)jx) * ksc);
        wx[k] = w2; sumx += w2;
    }

    const float* p = out129 + (size_t)b * (HO * WO);
    float r = 0.f;
#pragma unroll
    for (int ky = 0; ky < 4; ++ky) {
        if (wy[ky] == 0.f) continue;
        int jy = fy - 1 + ky;
        float rowv = 0.f;
#pragma unroll
        for (int kx = 0; kx < 4; ++kx) {
            if (wx[kx] == 0.f) continue;
            rowv += wx[kx] * p[jy * WO + (fx - 1 + kx)];
        }
        r += wy[ky] * rowv;
    }
    out[idx] = r / (sumy * sumx);
}

// ---------------------------------------------------------------------------
extern "C" void kernel_launch(void* const* d_in, const int* in_sizes, int n_in,
                              void* d_out, int out_size, void* d_ws, size_t ws_size,
                              hipStream_t stream) {
    const float* x1 = (const float*)d_in[0];   // (8,64,128,128)
    const float* x2 = (const float*)d_in[1];   // (8,64,60,60)
    float* out = (float*)d_out;

    float* ws     = (float*)d_ws;
    float* inv2   = ws;                               // 28800
    float* Sbuf   = inv2 + BB * HS * WS;              // 18432
    float* x1n    = Sbuf + BB * CC * 36;              // 8*64*19296 = 9879552
    float* part   = x1n + (size_t)BB * CC * PPL;      // 16*8*17028 = 2179584
    float* out129 = part + (size_t)G * BB * PPLANE;   // 133128

    k_norm1 <<<(BB * PPL) / 256, 256, 0, stream>>>(x1, x1n);
    k_inv2  <<<(BB * HS * WS) / 64, 256, 0, stream>>>(x2, inv2);
    k_fold  <<<BB * CC, 256, 0, stream>>>(x2, inv2, Sbuf);
    k_conv  <<<4 * BB * G, 256, 0, stream>>>(x1n, Sbuf, part);
    k_reduce<<<(BB * HO * WO + 255) / 256, 256, 0, stream>>>(part, out129);
    k_resize<<<(BB * HW1) / 256, 256, 0, stream>>>(out129, out);
}

// Round 4
// 137.414 us; speedup vs baseline: 1.0233x; 1.0233x over previous
//
#include <hip/hip_runtime.h>
#include <cstddef>

// Problem constants
#define BB   8
#define CC   64
#define H1   128
#define W1   128
#define HW1  (H1*W1)
#define HS   60
#define WS   60
#define HO   129
#define WO   129

// padded normalized-x1 plane
#define PWD  144            // padded width (floats), 16B aligned
#define PHT  134            // padded height
#define PPL  (PHT*PWD)      // 19296 floats per (b,c) plane

// conv tiling
#define G     16            // channel groups
#define CPG   4             // channels per group
#define T4    19            // float4 per LDS tile row
#define TROWS 70            // tile rows (64 outputs + 5 taps + 1 edge row)
#define NSLOT (TROWS*T4)    // 1330 float4 slots per buffer
#define PSTR  132           // partial plane row stride
#define PPLANE (HO*PSTR)    // 17028

// fused prep kernel
#define NCHUNK 15                   // 60 rows of x2 = 15 chunks x 4 rows
#define NBLK_NORM 603               // BB*PPL/256
#define NBLK_PRE  (BB*NCHUNK)       // 120

typedef unsigned int u32;
__device__ __forceinline__ void async_g2l(const float* g, float4* l) {
    __builtin_amdgcn_global_load_lds((const __attribute__((address_space(1))) u32*)g,
                                     (__attribute__((address_space(3))) u32*)l,
                                     16, 0, 0);
}

// ---------------------------------------------------------------------------
// Fused: x1 channel-norm -> padded planes  (blocks 0..602)
//        x2 inv-norm + patch-fold partials (blocks 603..722)
__global__ __launch_bounds__(256) void k_prep(const float* __restrict__ x1,
                                              const float* __restrict__ x2,
                                              float* __restrict__ x1n,
                                              float* __restrict__ Spart) {
    __shared__ float inv[240];
    int tid = threadIdx.x;

    if (blockIdx.x < NBLK_NORM) {
        // ---- normalize x1 into zero-padded planes ----
        int idx = blockIdx.x * 256 + tid;       // 154368 exactly
        int b  = idx / PPL;
        int pp = idx - b * PPL;
        int pr = pp / PWD, pc = pp - pr * PWD;
        int gy = pr - 3, gx = pc - 3;
        float* outp = x1n + (size_t)b * CC * PPL + pp;
        if ((unsigned)gy < 128u && (unsigned)gx < 128u) {
            const float* p = x1 + (size_t)b * CC * HW1 + gy * W1 + gx;
            float v[CC];
            float s = 0.f;
#pragma unroll
            for (int c = 0; c < CC; ++c) { v[c] = p[c * HW1]; s += v[c] * v[c]; }
            float iv = 1.0f / sqrtf(s);
#pragma unroll
            for (int c = 0; c < CC; ++c) outp[c * PPL] = v[c] * iv;
        } else {
#pragma unroll
            for (int c = 0; c < CC; ++c) outp[c * PPL] = 0.f;
        }
    } else {
        // ---- x2: inv-norm for 4 source rows, then fold partial bins ----
        int pb = blockIdx.x - NBLK_NORM;        // 0..119
        int b = pb / NCHUNK, chunk = pb - b * NCHUNK;
        int px0 = chunk * 240;                  // 4 source rows of 60

        if (tid < 240) {
            const float* p = x2 + (size_t)b * CC * (HS * WS) + px0 + tid;
            float s = 0.f;
#pragma unroll
            for (int c = 0; c < CC; ++c) { float v = p[c * (HS * WS)]; s += v * v; }
            inv[tid] = 1.0f / sqrtf(s);
        }
        __syncthreads();

        int c = tid >> 2, q = tid & 3;
        int row = chunk * 4 + q;                // global source row (hh)
        const float* px = x2 + ((size_t)b * CC + c) * (HS * WS) + row * WS;
        const float* iv = inv + q * 60;
        float acc[6] = {0, 0, 0, 0, 0, 0};
#pragma unroll
        for (int i = 0; i < 60; ++i)
            acc[i % 6] += px[i] * iv[i];        // i%6 is the dx bin

        float* sb = Spart + (((size_t)b * CC + c) * NCHUNK + chunk) * 36;
        int r0 = row % 6;                       // dy bin owned by this thread
#pragma unroll
        for (int j = 0; j < 6; ++j) sb[r0 * 6 + j] = acc[j];
        if (q < 2) {                            // zero the 2 dy bins absent here
            int rm = (chunk * 4 + 4 + q) % 6;
#pragma unroll
            for (int j = 0; j < 6; ++j) sb[rm * 6 + j] = 0.f;
        }
    }
}

// ---------------------------------------------------------------------------
// conv: 64x64 output tile (+ guarded edge row/col 128), 4 channels/block,
// async global->LDS double-buffered, 4x4(+edges) outputs per thread
__global__ __launch_bounds__(256) void k_conv(const float* __restrict__ x1n,
                                              const float* __restrict__ Spart,
                                              float* __restrict__ part) {
    int blk = blockIdx.x;            // 4*8*16 = 512
    int x0 = (blk & 1) * 64;
    int y0 = ((blk >> 1) & 1) * 64;
    int b  = (blk >> 2) & 7;
    int g  = blk >> 5;
    int tid = threadIdx.x;
    int tx = tid & 15, ty = tid >> 4;
    int wv = tid >> 6;

    __shared__ float4 lbuf[2][NSLOT];
    __shared__ float4 svf[CPG][9];

    // per-block S vectors: sum 15 chunk-partials per (channel, bin)
    if (tid < CPG * 36) {
        int ci = tid / 36, bin = tid - ci * 36;
        const float* sp = Spart + (((size_t)b * CC + g * CPG + ci) * NCHUNK) * 36 + bin;
        float s = 0.f;
#pragma unroll
        for (int k = 0; k < NCHUNK; ++k) s += sp[k * 36];
        ((float*)svf)[tid] = s;
    }

    // slot -> padded-plane offsets (channel-invariant)
    int off[6];
#pragma unroll
    for (int k = 0; k < 6; ++k) {
        int i = tid + 256 * k;
        int r = i / T4, c4 = i - r * T4;
        off[k] = (y0 + r) * PWD + x0 + 4 * c4;
    }

    const float* gbase = x1n + ((size_t)b * CC + g * CPG) * PPL;

    // prefetch channel 0 into buffer 0
#pragma unroll
    for (int k = 0; k < 5; ++k)
        async_g2l(gbase + off[k], &lbuf[0][wv * 64 + 256 * k]);
    if (tid < NSLOT - 1280)
        async_g2l(gbase + off[5], &lbuf[0][wv * 64 + 1280]);

    float acc[4][5] = {{0,0,0,0,0},{0,0,0,0,0},{0,0,0,0,0},{0,0,0,0,0}};
    float accE[5] = {0,0,0,0,0};
    const bool doC4 = (x0 == 64) && (tx == 15);
    const bool doR4 = (y0 == 64) && (ty == 15);

    for (int ci = 0; ci < CPG; ++ci) {
        __syncthreads();             // drains async loads for channel ci (+svf)

        if (ci + 1 < CPG) {          // prefetch next channel into other buffer
            const float* gp = gbase + (size_t)(ci + 1) * PPL;
            float4* dst = lbuf[(ci + 1) & 1];
#pragma unroll
            for (int k = 0; k < 5; ++k)
                async_g2l(gp + off[k], &dst[wv * 64 + 256 * k]);
            if (tid < NSLOT - 1280)
                async_g2l(gp + off[5], &dst[wv * 64 + 1280]);
        }

        float s[36];
        const float4* sp = (const float4*)svf[ci];
#pragma unroll
        for (int t = 0; t < 9; ++t) {
            float4 w = sp[t];
            s[4*t] = w.x; s[4*t+1] = w.y; s[4*t+2] = w.z; s[4*t+3] = w.w;
        }

        const float4* tb = lbuf[ci & 1];
#pragma unroll
        for (int rr = 0; rr < 9; ++rr) {
            const float4* rp = tb + (4 * ty + rr) * T4 + tx;
            float4 q0 = rp[0], q1 = rp[1], q2 = rp[2];
            float r[12] = {q0.x,q0.y,q0.z,q0.w, q1.x,q1.y,q1.z,q1.w,
                           q2.x,q2.y,q2.z,q2.w};
#pragma unroll
            for (int q = 0; q < 4; ++q) {
                int dy = rr - q;
                if (dy >= 0 && dy < 6) {
#pragma unroll
                    for (int j = 0; j < 4; ++j)
#pragma unroll
                        for (int dx = 0; dx < 6; ++dx)
                            acc[q][j] += r[j + dx] * s[dy * 6 + dx];
                    if (doC4) {
#pragma unroll
                        for (int dx = 0; dx < 6; ++dx)
                            acc[q][4] += r[4 + dx] * s[dy * 6 + dx];
                    }
                }
            }
            if (doR4 && rr >= 4) {
                int dy = rr - 4;
#pragma unroll
                for (int j = 0; j < 4; ++j)
#pragma unroll
                    for (int dx = 0; dx < 6; ++dx)
                        accE[j] += r[j + dx] * s[dy * 6 + dx];
                if (doC4) {
#pragma unroll
                    for (int dx = 0; dx < 6; ++dx)
                        accE[4] += r[4 + dx] * s[dy * 6 + dx];
                }
            }
        }
        if (doR4) {                  // window row rr=9 feeds edge row, dy=5
            const float4* rp = tb + (4 * ty + 9) * T4 + tx;
            float4 q0 = rp[0], q1 = rp[1], q2 = rp[2];
            float r[12] = {q0.x,q0.y,q0.z,q0.w, q1.x,q1.y,q1.z,q1.w,
                           q2.x,q2.y,q2.z,q2.w};
#pragma unroll
            for (int j = 0; j < 4; ++j)
#pragma unroll
                for (int dx = 0; dx < 6; ++dx)
                    accE[j] += r[j + dx] * s[30 + dx];
            if (doC4) {
#pragma unroll
                for (int dx = 0; dx < 6; ++dx)
                    accE[4] += r[4 + dx] * s[30 + dx];
            }
        }
    }

    float* pb = part + ((size_t)g * BB + b) * PPLANE;
    int orow = y0 + 4 * ty, ocol = x0 + 4 * tx;
#pragma unroll
    for (int q = 0; q < 4; ++q)
        *(float4*)(pb + (size_t)(orow + q) * PSTR + ocol) =
            make_float4(acc[q][0], acc[q][1], acc[q][2], acc[q][3]);
    if (doC4) {
#pragma unroll
        for (int q = 0; q < 4; ++q)
            pb[(size_t)(orow + q) * PSTR + 128] = acc[q][4];
    }
    if (doR4) {
        *(float4*)(pb + (size_t)128 * PSTR + ocol) =
            make_float4(accE[0], accE[1], accE[2], accE[3]);
        if (doC4) pb[(size_t)128 * PSTR + 128] = accE[4];
    }
}

// ---------------------------------------------------------------------------
// Fused reduce(16 partials, /3600) + bilinear-antialias resize 129->128.
// One block per 32x32 output tile; staged 36x36 g-summed region in LDS.
__global__ __launch_bounds__(256) void k_out(const float* __restrict__ part,
                                             float* __restrict__ out) {
    __shared__ float m[36 * 37];
    int blk  = blockIdx.x;          // 8 b x 16 tiles
    int b    = blk >> 4;
    int tile = blk & 15;
    int oy0 = (tile >> 2) * 32, ox0 = (tile & 3) * 32;
    int tid = threadIdx.x;
    int ry0 = oy0 - 1, rx0 = ox0 - 1;

    for (int i = tid; i < 36 * 36; i += 256) {
        int ly = i / 36, lx = i - ly * 36;
        int jy = min(max(ry0 + ly, 0), 128);
        int jx = min(max(rx0 + lx, 0), 128);
        const float* pp = part + (size_t)b * PPLANE + jy * PSTR + jx;
        float s = 0.f;
#pragma unroll
        for (int g = 0; g < G; ++g) s += pp[(size_t)g * BB * PPLANE];
        m[ly * 37 + lx] = s * (1.0f / 3600.0f);
    }
    __syncthreads();

    const float inv_scale = 129.0f / 128.0f;
    const float ksc       = 128.0f / 129.0f;

    int oy  = oy0 + (tid >> 3);
    int oxb = ox0 + (tid & 7) * 4;

    float sy = (oy + 0.5f) * inv_scale - 0.5f;
    int fy = (int)floorf(sy);
    float wy[4];
    float sumy = 0.f;
#pragma unroll
    for (int k = 0; k < 4; ++k) {
        int jy = fy - 1 + k;
        float w = 0.f;
        if (jy >= 0 && jy < HO) w = fmaxf(0.f, 1.0f - fabsf(sy - (float)jy) * ksc);
        wy[k] = w; sumy += w;
    }

    float res[4];
#pragma unroll
    for (int j = 0; j < 4; ++j) {
        int ox = oxb + j;
        float sx = (ox + 0.5f) * inv_scale - 0.5f;
        int fx = (int)floorf(sx);
        float wx[4];
        float sumx = 0.f;
#pragma unroll
        for (int k = 0; k < 4; ++k) {
            int jx = fx - 1 + k;
            float w = 0.f;
            if (jx >= 0 && jx < WO) w = fmaxf(0.f, 1.0f - fabsf(sx - (float)jx) * ksc);
            wx[k] = w; sumx += w;
        }
        float r = 0.f;
#pragma unroll
        for (int ky = 0; ky < 4; ++ky) {
            if (wy[ky] == 0.f) continue;
            int ly = fy - 1 + ky - ry0;
            float rowv = 0.f;
#pragma unroll
            for (int kx = 0; kx < 4; ++kx) {
                if (wx[kx] == 0.f) continue;
                int lx = fx - 1 + kx - rx0;
                rowv += wx[kx] * m[ly * 37 + lx];
            }
            r += wy[ky] * rowv;
        }
        res[j] = r / (sumy * sumx);
    }

    *(float4*)(out + (size_t)b * HW1 + oy * W1 + oxb) =
        make_float4(res[0], res[1], res[2], res[3]);
}

// ---------------------------------------------------------------------------
extern "C" void kernel_launch(void* const* d_in, const int* in_sizes, int n_in,
                              void* d_out, int out_size, void* d_ws, size_t ws_size,
                              hipStream_t stream) {
    const float* x1 = (const float*)d_in[0];   // (8,64,128,128)
    const float* x2 = (const float*)d_in[1];   // (8,64,60,60)
    float* out = (float*)d_out;

    float* ws    = (float*)d_ws;
    float* x1n   = ws;                                // 8*64*19296 = 9879552
    float* part  = x1n + (size_t)BB * CC * PPL;       // 16*8*17028 = 2179584
    float* Spart = part + (size_t)G * BB * PPLANE;    // 8*64*15*36 = 276480

    k_prep<<<NBLK_NORM + NBLK_PRE, 256, 0, stream>>>(x1, x2, x1n, Spart);
    k_conv<<<4 * BB * G, 256, 0, stream>>>(x1n, Spart, part);
    k_out <<<BB * 16, 256, 0, stream>>>(part, out);
}

// Round 5
// 130.181 us; speedup vs baseline: 1.0802x; 1.0556x over previous
//
#include <hip/hip_runtime.h>
#include <cstddef>

// Problem constants
#define BB   8
#define CC   64
#define H1   128
#define W1   128
#define HW1  (H1*W1)
#define HS   60
#define WS   60
#define HO   129
#define WO   129
#define NPIX (HS*WS)        // 3600

// U: 36 planes of [BB][HW1]
#define UPL  (BB*HW1)       // 131072 floats per t-plane

// ---------------------------------------------------------------------------
// inv-norm of x2 over channels: inv2[b,hw] = 1/||x2[b,:,hw]||
__global__ __launch_bounds__(256) void k_inv2(const float* __restrict__ x2,
                                              float* __restrict__ inv2) {
    int idx = blockIdx.x * 256 + threadIdx.x;   // 28800 (113 blocks)
    if (idx >= BB * NPIX) return;
    int b  = idx / NPIX;
    int hw = idx - b * NPIX;
    const float* p = x2 + (size_t)b * CC * NPIX + hw;
    float s = 0.f;
#pragma unroll
    for (int cc = 0; cc < CC; cc += 8) {
        float v0 = p[(cc+0)*NPIX], v1 = p[(cc+1)*NPIX];
        float v2 = p[(cc+2)*NPIX], v3 = p[(cc+3)*NPIX];
        float v4 = p[(cc+4)*NPIX], v5 = p[(cc+5)*NPIX];
        float v6 = p[(cc+6)*NPIX], v7 = p[(cc+7)*NPIX];
        s += v0*v0 + v1*v1 + v2*v2 + v3*v3 + v4*v4 + v5*v5 + v6*v6 + v7*v7;
    }
    inv2[idx] = 1.0f / sqrtf(s);
}

// fold 10x10 patch grid into 6x6 kernel per (b,c): S[b,c,dy*6+dx]
__global__ __launch_bounds__(256) void k_fold(const float* __restrict__ x2,
                                              const float* __restrict__ inv2,
                                              float* __restrict__ S) {
    __shared__ float bins[36];
    int tid = threadIdx.x;
    int bc  = blockIdx.x;            // 512 = b*64+c
    int b   = bc >> 6;
    if (tid < 36) bins[tid] = 0.f;
    __syncthreads();
    const float* px = x2 + (size_t)bc * NPIX;
    const float* pn = inv2 + b * NPIX;
    for (int i = tid; i < NPIX; i += 256) {
        int hh = i / WS, ww = i - hh * WS;
        int bin = (hh % 6) * 6 + (ww % 6);
        atomicAdd(&bins[bin], px[i] * pn[i]);
    }
    __syncthreads();
    if (tid < 36) S[bc * 36 + tid] = bins[tid];
}

// ---------------------------------------------------------------------------
// U[t][b][p] = inv1[b,p] * (1/3600) * sum_c x1[b,c,p] * S[b,c,t]
// inv1 computed in the same pass (x1 read exactly once).
// S is block-uniform -> scalar-cache loads.
__global__ __launch_bounds__(256) void k_gemm(const float* __restrict__ x1,
                                              const float* __restrict__ S,
                                              float* __restrict__ U) {
    int b = blockIdx.x >> 6;                    // 512 blocks: 8 b x 64 chunks
    int p = (blockIdx.x & 63) * 256 + threadIdx.x;

    const float* xp = x1 + (size_t)b * CC * HW1 + p;
    const float* Sb = S + (size_t)b * (CC * 36);   // uniform base

    float acc[36];
#pragma unroll
    for (int t = 0; t < 36; ++t) acc[t] = 0.f;
    float s2 = 0.f;

    for (int cc = 0; cc < CC; cc += 8) {
        float v[8];
#pragma unroll
        for (int j = 0; j < 8; ++j) v[j] = xp[(size_t)(cc + j) * HW1];
#pragma unroll
        for (int j = 0; j < 8; ++j) {
            const float* sj = Sb + (cc + j) * 36;   // uniform -> s_load
            float vv = v[j];
            s2 += vv * vv;
#pragma unroll
            for (int t = 0; t < 36; ++t) acc[t] += vv * sj[t];
        }
    }

    float inv = (1.0f / 3600.0f) / sqrtf(s2);
    float* up = U + (size_t)b * HW1 + p;
#pragma unroll
    for (int t = 0; t < 36; ++t) up[(size_t)t * UPL] = acc[t] * inv;
}

// ---------------------------------------------------------------------------
// Fused: out129 tile via 36-plane shifted gather of U, then bilinear
// antialias resize 129->128. One block per 16x16 output tile.
__global__ __launch_bounds__(256) void k_out(const float* __restrict__ U,
                                             float* __restrict__ out) {
    __shared__ float m[20 * 21];
    int blk  = blockIdx.x;           // 8 b x 64 tiles
    int b    = blk >> 6;
    int tile = blk & 63;
    int oy0 = (tile >> 3) * 16, ox0 = (tile & 7) * 16;
    int ry0 = oy0 - 1, rx0 = ox0 - 1;
    int tid = threadIdx.x;

    const float* Ub = U + (size_t)b * HW1;

    // stage m[ly][lx] = out129[clamp(ry0+ly), clamp(rx0+lx)]
    for (int i = tid; i < 400; i += 256) {
        int ly = i / 20, lx = i - ly * 20;
        int jy = min(max(ry0 + ly, 0), 128);
        int jx = min(max(rx0 + lx, 0), 128);
        float s = 0.f;
#pragma unroll
        for (int t = 0; t < 36; ++t) {
            int dy = t / 6, dx = t - dy * 6;
            int py = jy - 3 + dy, px = jx - 3 + dx;
            if ((unsigned)py < 128u && (unsigned)px < 128u)
                s += Ub[(size_t)t * UPL + py * W1 + px];
        }
        m[ly * 21 + lx] = s;
    }
    __syncthreads();

    const float inv_scale = 129.0f / 128.0f;
    const float ksc       = 128.0f / 129.0f;

    int oy = oy0 + (tid >> 4);
    int ox = ox0 + (tid & 15);

    float sy = (oy + 0.5f) * inv_scale - 0.5f;
    float sx = (ox + 0.5f) * inv_scale - 0.5f;
    int fy = (int)floorf(sy);
    int fx = (int)floorf(sx);

    float wy[4], wx[4];
    float sumy = 0.f, sumx = 0.f;
#pragma unroll
    for (int k = 0; k < 4; ++k) {
        int jy = fy - 1 + k;
        float w = 0.f;
        if (jy >= 0 && jy < HO) w = fmaxf(0.f, 1.0f - fabsf(sy - (float)jy) * ksc);
        wy[k] = w; sumy += w;
        int jx = fx - 1 + k;
        float w2 = 0.f;
        if (jx >= 0 && jx < WO) w2 = fmaxf(0.f, 1.0f - fabsf(sx - (float)jx) * ksc);
        wx[k] = w2; sumx += w2;
    }

    float r = 0.f;
#pragma unroll
    for (int ky = 0; ky < 4; ++ky) {
        if (wy[ky] == 0.f) continue;
        int ly = fy - 1 + ky - ry0;
        float rowv = 0.f;
#pragma unroll
        for (int kx = 0; kx < 4; ++kx) {
            if (wx[kx] == 0.f) continue;
            int lx = fx - 1 + kx - rx0;
            rowv += wx[kx] * m[ly * 21 + lx];
        }
        r += wy[ky] * rowv;
    }

    out[(size_t)b * HW1 + oy * W1 + ox] = r / (sumy * sumx);
}

// ---------------------------------------------------------------------------
extern "C" void kernel_launch(void* const* d_in, const int* in_sizes, int n_in,
                              void* d_out, int out_size, void* d_ws, size_t ws_size,
                              hipStream_t stream) {
    const float* x1 = (const float*)d_in[0];   // (8,64,128,128)
    const float* x2 = (const float*)d_in[1];   // (8,64,60,60)
    float* out = (float*)d_out;

    float* ws   = (float*)d_ws;
    float* inv2 = ws;                          // 28800
    float* Sbuf = inv2 + BB * NPIX;            // 8*64*36 = 18432
    float* U    = Sbuf + BB * CC * 36;         // 36*131072 = 4718592

    k_inv2<<<(BB * NPIX + 255) / 256, 256, 0, stream>>>(x2, inv2);
    k_fold<<<BB * CC, 256, 0, stream>>>(x2, inv2, Sbuf);
    k_gemm<<<BB * 64, 256, 0, stream>>>(x1, Sbuf, U);
    k_out <<<BB * 64, 256, 0, stream>>>(U, out);
}

// Round 6
// 128.375 us; speedup vs baseline: 1.0954x; 1.0141x over previous
//
#include <hip/hip_runtime.h>
#include <cstddef>

// Problem constants
#define BB   8
#define CC   64
#define H1   128
#define W1   128
#define HW1  (H1*W1)
#define HS   60
#define WS   60
#define HO   129
#define WO   129
#define NPIX (HS*WS)        // 3600

// U: 36 planes of [BB][HW1], stored fp16
#define UPL  (BB*HW1)       // 131072 elements per t-plane

typedef _Float16 f16;

// ---------------------------------------------------------------------------
// inv-norm of x2 over channels: inv2[b,hw] = 1/||x2[b,:,hw]||
__global__ __launch_bounds__(256) void k_inv2(const float* __restrict__ x2,
                                              float* __restrict__ inv2) {
    int idx = blockIdx.x * 256 + threadIdx.x;   // 28800 (113 blocks)
    if (idx >= BB * NPIX) return;
    int b  = idx / NPIX;
    int hw = idx - b * NPIX;
    const float* p = x2 + (size_t)b * CC * NPIX + hw;
    float s = 0.f;
#pragma unroll
    for (int cc = 0; cc < CC; cc += 8) {
        float v0 = p[(cc+0)*NPIX], v1 = p[(cc+1)*NPIX];
        float v2 = p[(cc+2)*NPIX], v3 = p[(cc+3)*NPIX];
        float v4 = p[(cc+4)*NPIX], v5 = p[(cc+5)*NPIX];
        float v6 = p[(cc+6)*NPIX], v7 = p[(cc+7)*NPIX];
        s += v0*v0 + v1*v1 + v2*v2 + v3*v3 + v4*v4 + v5*v5 + v6*v6 + v7*v7;
    }
    inv2[idx] = 1.0f / sqrtf(s);
}

// fold 10x10 patch grid into 6x6 kernel per (b,c): S[b,c,dy*6+dx]
__global__ __launch_bounds__(256) void k_fold(const float* __restrict__ x2,
                                              const float* __restrict__ inv2,
                                              float* __restrict__ S) {
    __shared__ float bins[36];
    int tid = threadIdx.x;
    int bc  = blockIdx.x;            // 512 = b*64+c
    int b   = bc >> 6;
    if (tid < 36) bins[tid] = 0.f;
    __syncthreads();
    const float* px = x2 + (size_t)bc * NPIX;
    const float* pn = inv2 + b * NPIX;
    for (int i = tid; i < NPIX; i += 256) {
        int hh = i / WS, ww = i - hh * WS;
        int bin = (hh % 6) * 6 + (ww % 6);
        atomicAdd(&bins[bin], px[i] * pn[i]);
    }
    __syncthreads();
    if (tid < 36) S[bc * 36 + tid] = bins[tid];
}

// ---------------------------------------------------------------------------
// U[t][b][p] = inv1[b,p] * (1/3600) * sum_c x1[b,c,p] * S[b,c,t]
// inv1 computed in the same pass (x1 read exactly once).
// S is block-uniform -> scalar-cache loads. U stored as fp16.
__global__ __launch_bounds__(256) void k_gemm(const float* __restrict__ x1,
                                              const float* __restrict__ S,
                                              f16* __restrict__ U) {
    int b = blockIdx.x >> 6;                    // 512 blocks: 8 b x 64 chunks
    int p = (blockIdx.x & 63) * 256 + threadIdx.x;

    const float* xp = x1 + (size_t)b * CC * HW1 + p;
    const float* Sb = S + (size_t)b * (CC * 36);   // uniform base

    float acc[36];
#pragma unroll
    for (int t = 0; t < 36; ++t) acc[t] = 0.f;
    float s2 = 0.f;

    for (int cc = 0; cc < CC; cc += 8) {
        float v[8];
#pragma unroll
        for (int j = 0; j < 8; ++j) v[j] = xp[(size_t)(cc + j) * HW1];
#pragma unroll
        for (int j = 0; j < 8; ++j) {
            const float* sj = Sb + (cc + j) * 36;   // uniform -> s_load
            float vv = v[j];
            s2 += vv * vv;
#pragma unroll
            for (int t = 0; t < 36; ++t) acc[t] += vv * sj[t];
        }
    }

    float inv = (1.0f / 3600.0f) / sqrtf(s2);
    f16* up = U + (size_t)b * HW1 + p;
#pragma unroll
    for (int t = 0; t < 36; ++t) up[(size_t)t * UPL] = (f16)(acc[t] * inv);
}

// ---------------------------------------------------------------------------
// Fused: out129 tile via 36-plane shifted gather of U (fp16), then bilinear
// antialias resize 129->128. One block per 16x16 output tile.
__global__ __launch_bounds__(256) void k_out(const f16* __restrict__ U,
                                             float* __restrict__ out) {
    __shared__ float m[20 * 21];
    int blk  = blockIdx.x;           // 8 b x 64 tiles
    int b    = blk >> 6;
    int tile = blk & 63;
    int oy0 = (tile >> 3) * 16, ox0 = (tile & 7) * 16;
    int ry0 = oy0 - 1, rx0 = ox0 - 1;
    int tid = threadIdx.x;

    const f16* Ub = U + (size_t)b * HW1;

    // stage m[ly][lx] = out129[clamp(ry0+ly), clamp(rx0+lx)]
    for (int i = tid; i < 400; i += 256) {
        int ly = i / 20, lx = i - ly * 20;
        int jy = min(max(ry0 + ly, 0), 128);
        int jx = min(max(rx0 + lx, 0), 128);
        float s = 0.f;
#pragma unroll
        for (int t = 0; t < 36; ++t) {
            int dy = t / 6, dx = t - dy * 6;
            int py = jy - 3 + dy, px = jx - 3 + dx;
            if ((unsigned)py < 128u && (unsigned)px < 128u)
                s += (float)Ub[(size_t)t * UPL + py * W1 + px];
        }
        m[ly * 21 + lx] = s;
    }
    __syncthreads();

    const float inv_scale = 129.0f / 128.0f;
    const float ksc       = 128.0f / 129.0f;

    int oy = oy0 + (tid >> 4);
    int ox = ox0 + (tid & 15);

    float sy = (oy + 0.5f) * inv_scale - 0.5f;
    float sx = (ox + 0.5f) * inv_scale - 0.5f;
    int fy = (int)floorf(sy);
    int fx = (int)floorf(sx);

    float wy[4], wx[4];
    float sumy = 0.f, sumx = 0.f;
#pragma unroll
    for (int k = 0; k < 4; ++k) {
        int jy = fy - 1 + k;
        float w = 0.f;
        if (jy >= 0 && jy < HO) w = fmaxf(0.f, 1.0f - fabsf(sy - (float)jy) * ksc);
        wy[k] = w; sumy += w;
        int jx = fx - 1 + k;
        float w2 = 0.f;
        if (jx >= 0 && jx < WO) w2 = fmaxf(0.f, 1.0f - fabsf(sx - (float)jx) * ksc);
        wx[k] = w2; sumx += w2;
    }

    float r = 0.f;
#pragma unroll
    for (int ky = 0; ky < 4; ++ky) {
        if (wy[ky] == 0.f) continue;
        int ly = fy - 1 + ky - ry0;
        float rowv = 0.f;
#pragma unroll
        for (int kx = 0; kx < 4; ++kx) {
            if (wx[kx] == 0.f) continue;
            int lx = fx - 1 + kx - rx0;
            rowv += wx[kx] * m[ly * 21 + lx];
        }
        r += wy[ky] * rowv;
    }

    out[(size_t)b * HW1 + oy * W1 + ox] = r / (sumy * sumx);
}

// ---------------------------------------------------------------------------
extern "C" void kernel_launch(void* const* d_in, const int* in_sizes, int n_in,
                              void* d_out, int out_size, void* d_ws, size_t ws_size,
                              hipStream_t stream) {
    const float* x1 = (const float*)d_in[0];   // (8,64,128,128)
    const float* x2 = (const float*)d_in[1];   // (8,64,60,60)
    float* out = (float*)d_out;

    float* ws   = (float*)d_ws;
    float* inv2 = ws;                          // 28800 floats
    float* Sbuf = inv2 + BB * NPIX;            // 18432 floats
    f16*   U    = (f16*)(Sbuf + BB * CC * 36); // 36*131072 halves (9.4 MB)

    k_inv2<<<(BB * NPIX + 255) / 256, 256, 0, stream>>>(x2, inv2);
    k_fold<<<BB * CC, 256, 0, stream>>>(x2, inv2, Sbuf);
    k_gemm<<<BB * 64, 256, 0, stream>>>(x1, Sbuf, U);
    k_out <<<BB * 64, 256, 0, stream>>>(U, out);
}